// Round 6
// baseline (1305.151 us; speedup 1.0000x reference)
//
#include <hip/hip_runtime.h>
#include <hip/hip_bf16.h>

#define SEQ 2048
#define BATCH 16
#define HID 512
#define OUT_DIM 10
#define NLAYERS 5
#define M_ROWS (SEQ * BATCH)   // 32768
#define N3H (3 * HID)          // 1536
#define GK HID                 // GEMM K

#define CHUNK 32
#define NSEG (SEQ / CHUNK)     // 64

typedef __attribute__((ext_vector_type(8))) _Float16 f16x8;
typedef __attribute__((ext_vector_type(4))) float f32x4;
typedef __attribute__((ext_vector_type(8))) unsigned short u16x8;

__device__ __forceinline__ unsigned short f2h(float x) {
  return __builtin_bit_cast(unsigned short, (_Float16)x);
}
__device__ __forceinline__ float h2f(unsigned short v) {
  return (float)__builtin_bit_cast(_Float16, v);
}

// ---------------- f32 -> f16 bulk convert (8 elems/thread) ----------------
__global__ __launch_bounds__(256) void cvt_f32_to_f16(const float* __restrict__ in,
                                                      unsigned short* __restrict__ out) {
  size_t i = ((size_t)blockIdx.x * 256 + threadIdx.x) * 8;
  float4 a = *(const float4*)(in + i);
  float4 b = *(const float4*)(in + i + 4);
  u16x8 r;
  r[0] = f2h(a.x); r[1] = f2h(a.y); r[2] = f2h(a.z); r[3] = f2h(a.w);
  r[4] = f2h(b.x); r[5] = f2h(b.y); r[6] = f2h(b.z); r[7] = f2h(b.w);
  *(u16x8*)(out + i) = r;
}

// ---------------- W-stationary zero-barrier f16 MFMA GEMM ----------------
// C[m][n] = sum_k A[m][k] * W[n][k].  A:[M][512], W:[1536][512], C:[M][1536].
// Block: 256 thr (4 waves), W tile [64n][512k] resident in LDS (pad->520),
// each block does 2 m-passes of 256 rows (wave w owns 64 rows x 64 cols).
// K-loop has NO barriers: A-frags load direct global->reg (line-coalesced:
// per instr 16 rows x one full 64B line), W-frags from LDS (8/bank min).
// Grid 64bm x 24bn, XCD-chunked swizzle: per-XCD A slice = 8*512 rows = 4 MiB
// = one L2; W (1.5 MiB/layer) L2-hot everywhere.
__global__ __launch_bounds__(256) void gemm_wstat(const unsigned short* __restrict__ A,
                                                  const unsigned short* __restrict__ W,
                                                  unsigned short* __restrict__ C) {
  __shared__ unsigned short wlds[64][520];
  const int tid = threadIdx.x;
  const int nwg = 64 * 24;                 // 1536
  const int cpx = nwg / 8;                 // 192 per XCD (bijective: 1536 % 8 == 0)
  const int swz = (blockIdx.x % 8) * cpx + blockIdx.x / 8;
  const int bm = swz / 24;
  const int bn = swz % 24;
  const int lane = tid & 63;
  const int wid = tid >> 6;

  // ---- load W tile [64][512] -> LDS once (coalesced: 4 threads per 1KB row)
  {
    const unsigned short* Wg = W + (size_t)bn * 64 * GK;
    const int r = tid >> 2;       // 0..63
    const int q = tid & 3;        // k-quarter
#pragma unroll
    for (int i = 0; i < 16; ++i) {
      int k = q * 128 + i * 8;
      *(u16x8*)&wlds[r][k] = *(const u16x8*)(Wg + (size_t)r * GK + k);
    }
  }
  __syncthreads();  // the only barrier

  const int fr = lane & 15;        // fragment row (m for A, n for W)
  const int ko = (lane >> 4) * 8;  // k offset (8 contiguous)

#pragma unroll 1
  for (int p = 0; p < 2; ++p) {
    const size_t rowg0 = (size_t)bm * 512 + p * 256 + wid * 64;
    const unsigned short* Ap = A + (rowg0 + fr) * GK + ko;

    f32x4 acc[4][4];
#pragma unroll
    for (int i = 0; i < 4; ++i)
#pragma unroll
      for (int j = 0; j < 4; ++j) acc[i][j] = (f32x4){0.f, 0.f, 0.f, 0.f};

    f16x8 acur[4];
#pragma unroll
    for (int mt = 0; mt < 4; ++mt)
      acur[mt] = *(const f16x8*)(Ap + (size_t)mt * 16 * GK);

#pragma unroll
    for (int kt = 0; kt < 15; ++kt) {
      f16x8 anext[4];
#pragma unroll
      for (int mt = 0; mt < 4; ++mt)
        anext[mt] = *(const f16x8*)(Ap + (size_t)mt * 16 * GK + (kt + 1) * 32);
      f16x8 wf[4];
#pragma unroll
      for (int nt = 0; nt < 4; ++nt)
        wf[nt] = *(const f16x8*)&wlds[nt * 16 + fr][kt * 32 + ko];
#pragma unroll
      for (int mt = 0; mt < 4; ++mt)
#pragma unroll
        for (int nt = 0; nt < 4; ++nt)
          acc[mt][nt] = __builtin_amdgcn_mfma_f32_16x16x32_f16(acur[mt], wf[nt], acc[mt][nt], 0, 0, 0);
#pragma unroll
      for (int mt = 0; mt < 4; ++mt) acur[mt] = anext[mt];
    }
    {  // kt = 15 (no prefetch)
      f16x8 wf[4];
#pragma unroll
      for (int nt = 0; nt < 4; ++nt)
        wf[nt] = *(const f16x8*)&wlds[nt * 16 + fr][15 * 32 + ko];
#pragma unroll
      for (int mt = 0; mt < 4; ++mt)
#pragma unroll
        for (int nt = 0; nt < 4; ++nt)
          acc[mt][nt] = __builtin_amdgcn_mfma_f32_16x16x32_f16(acur[mt], wf[nt], acc[mt][nt], 0, 0, 0);
    }

    // ---- epilogue: direct stores (C/D map: col=lane&15, row=(lane>>4)*4+j)
    const int er = (lane >> 4) * 4;
#pragma unroll
    for (int mt = 0; mt < 4; ++mt)
#pragma unroll
      for (int nt = 0; nt < 4; ++nt) {
        const size_t rb = rowg0 + mt * 16 + er;
        const int cg = bn * 64 + nt * 16 + fr;
#pragma unroll
        for (int j = 0; j < 4; ++j)
          C[(rb + j) * N3H + cg] = f2h(acc[mt][nt][j]);
      }
  }
}

// ---------------- Segment-parallel SRU scan (f16 data, f32 math) ----------------
__global__ __launch_bounds__(256) void scan_pass1(const unsigned short* __restrict__ U,
                                                  const float* __restrict__ bias,
                                                  float* __restrict__ Fseg,
                                                  float* __restrict__ Cseg) {
  int t = blockIdx.x * 256 + threadIdx.x;   // (s, b, h)
  int h = t & (HID - 1);
  int b = (t >> 9) & (BATCH - 1);
  int s = t >> 13;
  const float bfv = bias[h];
  const unsigned short* Up = U + (size_t)(s * CHUNK) * BATCH * N3H + (size_t)b * N3H + h;
  float F = 1.f, c = 0.f;
#pragma unroll 8
  for (int i = 0; i < CHUNK; ++i) {
    float xt = h2f(Up[0]);
    float zf = h2f(Up[HID]);
    float f = 1.f / (1.f + __expf(-(zf + bfv)));
    c = f * c + (1.f - f) * xt;
    F *= f;
    Up += BATCH * N3H;
  }
  size_t o = ((size_t)s * BATCH + b) * HID + h;
  Fseg[o] = F;
  Cseg[o] = c;
}

// per chain: serial scan over segment summaries; writes the INCOMING carry
// for each segment in-place into Cseg.
__global__ __launch_bounds__(256) void scan_mid(const float* __restrict__ Fseg,
                                                float* Cseg) {
  int t = blockIdx.x * 256 + threadIdx.x;   // 0..8191
  float c = 0.f;
#pragma unroll 4
  for (int s = 0; s < NSEG; ++s) {
    size_t o = (size_t)s * BATCH * HID + t;
    float F = Fseg[o], Cv = Cseg[o];
    Cseg[o] = c;          // incoming carry for segment s
    c = F * c + Cv;
  }
}

// pass3: apply carry, recompute gates, highway; in-place on the f16 h buffer
// (each element is read then written by the same thread in the same iter).
__global__ __launch_bounds__(256) void scan_pass3(const unsigned short* __restrict__ U,
                                                  const float* __restrict__ bias,
                                                  const float* __restrict__ Cin,
                                                  unsigned short* hb) {
  int t = blockIdx.x * 256 + threadIdx.x;
  int h = t & (HID - 1);
  int b = (t >> 9) & (BATCH - 1);
  int s = t >> 13;
  const float bfv = bias[h];
  const float brv = bias[HID + h];
  float c = Cin[(size_t)s * BATCH * HID + (b << 9) + h];
  const unsigned short* Up = U + (size_t)(s * CHUNK) * BATCH * N3H + (size_t)b * N3H + h;
  unsigned short* hp = hb + (size_t)(s * CHUNK) * BATCH * HID + (b << 9) + h;
#pragma unroll 4
  for (int i = 0; i < CHUNK; ++i) {
    float xt = h2f(Up[0]);
    float zf = h2f(Up[HID]);
    float zr = h2f(Up[2 * HID]);
    float xv = h2f(hp[0]);
    float f = 1.f / (1.f + __expf(-(zf + bfv)));
    float r = 1.f / (1.f + __expf(-(zr + brv)));
    c = f * c + (1.f - f) * xt;
    hp[0] = f2h(r * c + (1.f - r) * xv);
    Up += BATCH * N3H;
    hp += BATCH * HID;
  }
}

// ---------------- FC head (f16 H, f32 math) ----------------
#define FCR 16
__global__ __launch_bounds__(256) void fc_kernel(const unsigned short* __restrict__ H,
                                                 const float* __restrict__ W,
                                                 const float* __restrict__ bv,
                                                 float* __restrict__ out) {
  __shared__ float hs[FCR][516];
  __shared__ float ws[OUT_DIM][516];
  const int tid = threadIdx.x;
  const size_t m0 = (size_t)blockIdx.x * FCR;
#pragma unroll
  for (int i = 0; i < 4; ++i) {
    int f = tid + i * 256;
    int row = f >> 6;     // 0..15
    int kq = f & 63;      // 8-elem group
    u16x8 v = *(const u16x8*)(H + (m0 + row) * 512 + kq * 8);
#pragma unroll
    for (int j = 0; j < 8; ++j) hs[row][kq * 8 + j] = h2f(v[j]);
  }
#pragma unroll
  for (int i = 0; i < 5; ++i) {
    int f = tid + i * 256;
    int row = f >> 7;     // 0..9
    int kq = f & 127;
    float4 v = *(const float4*)(W + row * 512 + kq * 4);
    *(float4*)&ws[row][kq * 4] = v;
  }
  __syncthreads();
  if (tid < FCR * OUT_DIM) {
    int row = tid / OUT_DIM;
    int o = tid - row * OUT_DIM;
    float acc = bv[o];
#pragma unroll 8
    for (int k = 0; k < 512; ++k) acc += hs[row][k] * ws[o][k];
    out[(m0 + row) * OUT_DIM + o] = acc;
  }
}

extern "C" void kernel_launch(void* const* d_in, const int* in_sizes, int n_in,
                              void* d_out, int out_size, void* d_ws, size_t ws_size,
                              hipStream_t stream) {
  const float* x   = (const float*)d_in[0];  // [2048][16][512]
  const float* Ws  = (const float*)d_in[1];  // [5][1536][512]
  const float* bs  = (const float*)d_in[2];  // [5][1024]
  const float* fcW = (const float*)d_in[3];  // [10][512]
  const float* fcb = (const float*)d_in[4];  // [10]
  float* out = (float*)d_out;

  char* ws = (char*)d_ws;
  const size_t MiB = 1024 * 1024;
  unsigned short* Ub = (unsigned short*)ws;                  // 96 MiB: [M][1536] f16
  unsigned short* hb = (unsigned short*)(ws + 96 * MiB);     // 32 MiB: [M][512] f16
  unsigned short* Wh = (unsigned short*)(ws + 128 * MiB);    // 7.5 MiB: [5][1536][512] f16
  float*        Fseg = (float*)(ws + 136 * MiB);             // 2 MiB
  float*        Cseg = (float*)(ws + 138 * MiB);             // 2 MiB
  // total 140 MiB <= 256 MiB workspace

  // one-time converts (per call; inputs never mutated)
  cvt_f32_to_f16<<<(NLAYERS * N3H * HID) / (256 * 8), 256, 0, stream>>>(Ws, Wh);
  cvt_f32_to_f16<<<(M_ROWS * HID) / (256 * 8), 256, 0, stream>>>(x, hb);

  for (int l = 0; l < NLAYERS; ++l) {
    gemm_wstat<<<64 * 24, 256, 0, stream>>>(hb, Wh + (size_t)l * N3H * HID, Ub);
    const float* bias = bs + (size_t)l * 2 * HID;
    int nthr = BATCH * HID * NSEG;  // 524288
    scan_pass1<<<nthr / 256, 256, 0, stream>>>(Ub, bias, Fseg, Cseg);
    scan_mid<<<BATCH * HID / 256, 256, 0, stream>>>(Fseg, Cseg);
    scan_pass3<<<nthr / 256, 256, 0, stream>>>(Ub, bias, Cseg, hb);
  }
  fc_kernel<<<M_ROWS / FCR, 256, 0, stream>>>(hb, fcW, fcb, out);
}

// Round 7
// 665.158 us; speedup vs baseline: 1.9622x; 1.9622x over previous
//
#include <hip/hip_runtime.h>
#include <hip/hip_bf16.h>

#define SEQ 2048
#define BATCH 16
#define HID 512
#define OUT_DIM 10
#define NLAYERS 5
#define M_ROWS (SEQ * BATCH)   // 32768
#define N3H (3 * HID)          // 1536
#define GK HID                 // GEMM K

#define CHUNK 32
#define NSEG (SEQ / CHUNK)     // 64

typedef __attribute__((ext_vector_type(8))) _Float16 f16x8;
typedef __attribute__((ext_vector_type(4))) float f32x4;
typedef __attribute__((ext_vector_type(8))) unsigned short u16x8;
typedef __attribute__((ext_vector_type(4))) unsigned short u16x4;

__device__ __forceinline__ unsigned short f2h(float x) {
  return __builtin_bit_cast(unsigned short, (_Float16)x);
}
__device__ __forceinline__ float h2f(unsigned short v) {
  return (float)__builtin_bit_cast(_Float16, v);
}

// ---------------- f32 -> f16 bulk convert (8 elems/thread) ----------------
__global__ __launch_bounds__(256) void cvt_f32_to_f16(const float* __restrict__ in,
                                                      unsigned short* __restrict__ out) {
  size_t i = ((size_t)blockIdx.x * 256 + threadIdx.x) * 8;
  float4 a = *(const float4*)(in + i);
  float4 b = *(const float4*)(in + i + 4);
  u16x8 r;
  r[0] = f2h(a.x); r[1] = f2h(a.y); r[2] = f2h(a.z); r[3] = f2h(a.w);
  r[4] = f2h(b.x); r[5] = f2h(b.y); r[6] = f2h(b.z); r[7] = f2h(b.w);
  *(u16x8*)(out + i) = r;
}

// ---------------- f16 MFMA GEMM (R5 structure: 2-phase dbuf, 128x128) ----------------
// C[m][n] = sum_k A[m][k] * B[n][k]. A:[M][512], B:[1536][512] (B^T), C:[M][1536] f16.
// 1-D grid, bijective XCD-chunked swizzle (nwg=3072 % 8 == 0).
__global__ __launch_bounds__(256) void gemm_mfma(const unsigned short* __restrict__ A,
                                                 const unsigned short* __restrict__ B,
                                                 unsigned short* __restrict__ C) {
  __shared__ unsigned short lds[2][8192];  // [buf]: A tile 128x32 @0, B tile @4096
  const int tid = threadIdx.x;
  const int nwg = (M_ROWS / 128) * (N3H / 128);      // 3072
  const int cpx = nwg / 8;                           // 384
  const int swz = (blockIdx.x % 8) * cpx + blockIdx.x / 8;
  const int bm = swz / (N3H / 128);
  const int bn = swz % (N3H / 128);
  const int lane = tid & 63;
  const int wid = tid >> 6;
  const int wm = (wid >> 1) * 64, wn = (wid & 1) * 64;

  const unsigned short* Ag = A + (size_t)bm * 128 * GK;
  const unsigned short* Bg = B + (size_t)bn * 128 * GK;

  const int s0 = tid, s1 = tid + 256;
  const int r0 = s0 >> 2, c0 = (s0 & 3) * 8;
  const int r1 = s1 >> 2, c1 = (s1 & 3) * 8;

  const int fr = lane & 15;         // fragment row (M for A, N for B)
  const int ko = (lane >> 4) * 8;   // fragment k offset (8 contiguous)

  f32x4 acc[4][4];
#pragma unroll
  for (int i = 0; i < 4; ++i)
#pragma unroll
    for (int j = 0; j < 4; ++j) acc[i][j] = (f32x4){0.f, 0.f, 0.f, 0.f};

#define STAGE(buf, k0)                                                                              \
  {                                                                                                 \
    __builtin_amdgcn_global_load_lds(                                                               \
        (const __attribute__((address_space(1))) void*)(Ag + (size_t)r0 * GK + (k0) + c0),          \
        (__attribute__((address_space(3))) void*)&lds[buf][s0 * 8], 16, 0, 0);                      \
    __builtin_amdgcn_global_load_lds(                                                               \
        (const __attribute__((address_space(1))) void*)(Ag + (size_t)r1 * GK + (k0) + c1),          \
        (__attribute__((address_space(3))) void*)&lds[buf][s1 * 8], 16, 0, 0);                      \
    __builtin_amdgcn_global_load_lds(                                                               \
        (const __attribute__((address_space(1))) void*)(Bg + (size_t)r0 * GK + (k0) + c0),          \
        (__attribute__((address_space(3))) void*)&lds[buf][4096 + s0 * 8], 16, 0, 0);               \
    __builtin_amdgcn_global_load_lds(                                                               \
        (const __attribute__((address_space(1))) void*)(Bg + (size_t)r1 * GK + (k0) + c1),          \
        (__attribute__((address_space(3))) void*)&lds[buf][4096 + s1 * 8], 16, 0, 0);               \
  }

  STAGE(0, 0);
  __syncthreads();
  int cur = 0;
#pragma unroll 1
  for (int kt = 0; kt < GK / 32; ++kt) {
    if (kt + 1 < GK / 32) STAGE(cur ^ 1, (kt + 1) * 32);
    f16x8 af[4], bfr[4];
#pragma unroll
    for (int t = 0; t < 4; ++t) {
      af[t]  = *(const f16x8*)&lds[cur][(wm + t * 16 + fr) * 32 + ko];
      bfr[t] = *(const f16x8*)&lds[cur][4096 + (wn + t * 16 + fr) * 32 + ko];
    }
#pragma unroll
    for (int mt = 0; mt < 4; ++mt)
#pragma unroll
      for (int nt = 0; nt < 4; ++nt)
        acc[mt][nt] = __builtin_amdgcn_mfma_f32_16x16x32_f16(af[mt], bfr[nt], acc[mt][nt], 0, 0, 0);
    if (kt + 1 < GK / 32) {
      __syncthreads();
      cur ^= 1;
    }
  }
#undef STAGE

  // ---- coalesced C-write via LDS transpose (reuse staging LDS: 32 KB) ----
  __syncthreads();
  unsigned short* cl = &lds[0][0];  // 128x128 f16 tile, row-major
  const int er = (lane >> 4) * 4;   // C/D layout: col=lane&15, row=(lane>>4)*4+reg
#pragma unroll
  for (int mt = 0; mt < 4; ++mt)
#pragma unroll
    for (int nt = 0; nt < 4; ++nt) {
      const int row = wm + mt * 16 + er;
      const int col = wn + nt * 16 + fr;
#pragma unroll
      for (int j = 0; j < 4; ++j) cl[(row + j) * 128 + col] = f2h(acc[mt][nt][j]);
    }
  __syncthreads();
  unsigned short* Cb = C + (size_t)bm * 128 * N3H + bn * 128;
#pragma unroll
  for (int i = 0; i < 8; ++i) {
    int flat = i * 2048 + tid * 8;
    int r = flat >> 7, c = flat & 127;
    *(u16x8*)(Cb + (size_t)r * N3H + c) = *(const u16x8*)&cl[flat];
  }
}

// ---------------- Segment-parallel SRU scan (f16 data, f32 math, 4h/thread) ----------------
// pass1: thread = (s, b, hq); hq covers 4 adjacent h. 131072 threads.
__global__ __launch_bounds__(256) void scan_pass1(const unsigned short* __restrict__ U,
                                                  const float* __restrict__ bias,
                                                  float* __restrict__ Fseg,
                                                  float* __restrict__ Cseg) {
  int t = blockIdx.x * 256 + threadIdx.x;
  int hq = t & 127;
  int b = (t >> 7) & (BATCH - 1);
  int s = t >> 11;
  int h0 = hq * 4;
  float4 bf4 = *(const float4*)(bias + h0);
  const float bfv[4] = {bf4.x, bf4.y, bf4.z, bf4.w};
  const unsigned short* Up = U + (size_t)(s * CHUNK) * BATCH * N3H + (size_t)b * N3H + h0;
  float F[4] = {1.f, 1.f, 1.f, 1.f}, c[4] = {0.f, 0.f, 0.f, 0.f};
#pragma unroll 4
  for (int i = 0; i < CHUNK; ++i) {
    u16x4 xt = *(const u16x4*)(Up);
    u16x4 zf = *(const u16x4*)(Up + HID);
#pragma unroll
    for (int j = 0; j < 4; ++j) {
      float f = 1.f / (1.f + __expf(-(h2f(zf[j]) + bfv[j])));
      c[j] = f * c[j] + (1.f - f) * h2f(xt[j]);
      F[j] *= f;
    }
    Up += BATCH * N3H;
  }
  size_t o = ((size_t)s * BATCH + b) * HID + h0;
  *(float4*)(Fseg + o) = (float4){F[0], F[1], F[2], F[3]};
  *(float4*)(Cseg + o) = (float4){c[0], c[1], c[2], c[3]};
}

// mid: thread owns 4 chains; serial over NSEG summaries; writes INCOMING carry
// in-place into Cseg.
__global__ __launch_bounds__(256) void scan_mid(const float* __restrict__ Fseg,
                                                float* Cseg) {
  int t = blockIdx.x * 256 + threadIdx.x;   // 0..2047, chain group
  float c[4] = {0.f, 0.f, 0.f, 0.f};
#pragma unroll 4
  for (int s = 0; s < NSEG; ++s) {
    size_t o = (size_t)s * BATCH * HID + t * 4;
    float4 F = *(const float4*)(Fseg + o);
    float4 Cv = *(const float4*)(Cseg + o);
    *(float4*)(Cseg + o) = (float4){c[0], c[1], c[2], c[3]};
    c[0] = F.x * c[0] + Cv.x;
    c[1] = F.y * c[1] + Cv.y;
    c[2] = F.z * c[2] + Cv.z;
    c[3] = F.w * c[3] + Cv.w;
  }
}

// pass3: apply carry, recompute gates, highway; in-place on f16 h buffer.
__global__ __launch_bounds__(256) void scan_pass3(const unsigned short* __restrict__ U,
                                                  const float* __restrict__ bias,
                                                  const float* __restrict__ Cin,
                                                  unsigned short* hb) {
  int t = blockIdx.x * 256 + threadIdx.x;
  int hq = t & 127;
  int b = (t >> 7) & (BATCH - 1);
  int s = t >> 11;
  int h0 = hq * 4;
  float4 bf4 = *(const float4*)(bias + h0);
  float4 br4 = *(const float4*)(bias + HID + h0);
  const float bfv[4] = {bf4.x, bf4.y, bf4.z, bf4.w};
  const float brv[4] = {br4.x, br4.y, br4.z, br4.w};
  float4 ci = *(const float4*)(Cin + ((size_t)s * BATCH + b) * HID + h0);
  float c[4] = {ci.x, ci.y, ci.z, ci.w};
  const unsigned short* Up = U + (size_t)(s * CHUNK) * BATCH * N3H + (size_t)b * N3H + h0;
  unsigned short* hp = hb + (size_t)(s * CHUNK) * BATCH * HID + ((size_t)b << 9) + h0;
#pragma unroll 4
  for (int i = 0; i < CHUNK; ++i) {
    u16x4 xt = *(const u16x4*)(Up);
    u16x4 zf = *(const u16x4*)(Up + HID);
    u16x4 zr = *(const u16x4*)(Up + 2 * HID);
    u16x4 hv = *(const u16x4*)(hp);
    u16x4 ho;
#pragma unroll
    for (int j = 0; j < 4; ++j) {
      float f = 1.f / (1.f + __expf(-(h2f(zf[j]) + bfv[j])));
      float r = 1.f / (1.f + __expf(-(h2f(zr[j]) + brv[j])));
      c[j] = f * c[j] + (1.f - f) * h2f(xt[j]);
      ho[j] = f2h(r * c[j] + (1.f - r) * h2f(hv[j]));
    }
    *(u16x4*)(hp) = ho;
    Up += BATCH * N3H;
    hp += BATCH * HID;
  }
}

// ---------------- FC head (f16 H, f32 math) ----------------
#define FCR 16
__global__ __launch_bounds__(256) void fc_kernel(const unsigned short* __restrict__ H,
                                                 const float* __restrict__ W,
                                                 const float* __restrict__ bv,
                                                 float* __restrict__ out) {
  __shared__ float hs[FCR][516];
  __shared__ float ws[OUT_DIM][516];
  const int tid = threadIdx.x;
  const size_t m0 = (size_t)blockIdx.x * FCR;
#pragma unroll
  for (int i = 0; i < 4; ++i) {
    int f = tid + i * 256;
    int row = f >> 6;     // 0..15
    int kq = f & 63;      // 8-elem group
    u16x8 v = *(const u16x8*)(H + (m0 + row) * 512 + kq * 8);
#pragma unroll
    for (int j = 0; j < 8; ++j) hs[row][kq * 8 + j] = h2f(v[j]);
  }
#pragma unroll
  for (int i = 0; i < 5; ++i) {
    int f = tid + i * 256;
    int row = f >> 7;     // 0..9
    int kq = f & 127;
    float4 v = *(const float4*)(W + row * 512 + kq * 4);
    *(float4*)&ws[row][kq * 4] = v;
  }
  __syncthreads();
  if (tid < FCR * OUT_DIM) {
    int row = tid / OUT_DIM;
    int o = tid - row * OUT_DIM;
    float acc = bv[o];
#pragma unroll 8
    for (int k = 0; k < 512; ++k) acc += hs[row][k] * ws[o][k];
    out[(m0 + row) * OUT_DIM + o] = acc;
  }
}

extern "C" void kernel_launch(void* const* d_in, const int* in_sizes, int n_in,
                              void* d_out, int out_size, void* d_ws, size_t ws_size,
                              hipStream_t stream) {
  const float* x   = (const float*)d_in[0];  // [2048][16][512]
  const float* Ws  = (const float*)d_in[1];  // [5][1536][512]
  const float* bs  = (const float*)d_in[2];  // [5][1024]
  const float* fcW = (const float*)d_in[3];  // [10][512]
  const float* fcb = (const float*)d_in[4];  // [10]
  float* out = (float*)d_out;

  char* ws = (char*)d_ws;
  const size_t MiB = 1024 * 1024;
  unsigned short* Ub = (unsigned short*)ws;                  // 96 MiB: [M][1536] f16
  unsigned short* hb = (unsigned short*)(ws + 96 * MiB);     // 32 MiB: [M][512] f16
  unsigned short* Wh = (unsigned short*)(ws + 128 * MiB);    // 7.5 MiB: [5][1536][512] f16
  float*        Fseg = (float*)(ws + 136 * MiB);             // 2 MiB
  float*        Cseg = (float*)(ws + 138 * MiB);             // 2 MiB
  // total 140 MiB <= 256 MiB workspace

  // one-time converts (per call; inputs never mutated)
  cvt_f32_to_f16<<<(NLAYERS * N3H * HID) / (256 * 8), 256, 0, stream>>>(Ws, Wh);
  cvt_f32_to_f16<<<(M_ROWS * HID) / (256 * 8), 256, 0, stream>>>(x, hb);

  for (int l = 0; l < NLAYERS; ++l) {
    gemm_mfma<<<(M_ROWS / 128) * (N3H / 128), 256, 0, stream>>>(
        hb, Wh + (size_t)l * N3H * HID, Ub);
    const float* bias = bs + (size_t)l * 2 * HID;
    int nthr = NSEG * BATCH * 128;   // 131072 threads (4h each)
    scan_pass1<<<nthr / 256, 256, 0, stream>>>(Ub, bias, Fseg, Cseg);
    scan_mid<<<BATCH * HID / (256 * 4), 256, 0, stream>>>(Fseg, Cseg);
    scan_pass3<<<nthr / 256, 256, 0, stream>>>(Ub, bias, Cseg, hb);
  }
  fc_kernel<<<M_ROWS / FCR, 256, 0, stream>>>(hb, fcW, fcb, out);
}

// Round 8
// 645.889 us; speedup vs baseline: 2.0207x; 1.0298x over previous
//
#include <hip/hip_runtime.h>
#include <hip/hip_bf16.h>

#define SEQ 2048
#define BATCH 16
#define HID 512
#define OUT_DIM 10
#define NLAYERS 5
#define M_ROWS (SEQ * BATCH)   // 32768
#define N3H (3 * HID)          // 1536
#define GK HID                 // GEMM K

#define CHUNK 32
#define NSEG (SEQ / CHUNK)     // 64

typedef __attribute__((ext_vector_type(8))) _Float16 f16x8;
typedef __attribute__((ext_vector_type(4))) float f32x4;
typedef __attribute__((ext_vector_type(8))) unsigned short u16x8;

__device__ __forceinline__ unsigned short f2h(float x) {
  return __builtin_bit_cast(unsigned short, (_Float16)x);
}
__device__ __forceinline__ float h2f(unsigned short v) {
  return (float)__builtin_bit_cast(_Float16, v);
}
__device__ __forceinline__ float sigm(float x) { return 1.f / (1.f + __expf(-x)); }

// ---------------- f32 -> f16 bulk convert (8 elems/thread) ----------------
__global__ __launch_bounds__(256) void cvt_f32_to_f16(const float* __restrict__ in,
                                                      unsigned short* __restrict__ out) {
  size_t i = ((size_t)blockIdx.x * 256 + threadIdx.x) * 8;
  float4 a = *(const float4*)(in + i);
  float4 b = *(const float4*)(in + i + 4);
  u16x8 r;
  r[0] = f2h(a.x); r[1] = f2h(a.y); r[2] = f2h(a.z); r[3] = f2h(a.w);
  r[4] = f2h(b.x); r[5] = f2h(b.y); r[6] = f2h(b.z); r[7] = f2h(b.w);
  *(u16x8*)(out + i) = r;
}

// ---------------- f16 MFMA GEMM (2-phase dbuf, 128x128, padded epilogue) ----------------
// C[m][n] = sum_k A[m][k] * B[n][k]. A:[M][512], B:[1536][512] (B^T), C:[M][1536] f16.
__global__ __launch_bounds__(256) void gemm_mfma(const unsigned short* __restrict__ A,
                                                 const unsigned short* __restrict__ B,
                                                 unsigned short* __restrict__ C) {
  // staging: A tile at [buf][0..4095], B tile at [buf][4096..8191].
  // extra 512/buf so the C-transpose (128x136 = 17408 f16) fits the union.
  __shared__ unsigned short lds[2][8704];
  const int tid = threadIdx.x;
  const int nwg = (M_ROWS / 128) * (N3H / 128);      // 3072
  const int cpx = nwg / 8;                           // 384 (bijective: 3072 % 8 == 0)
  const int swz = (blockIdx.x % 8) * cpx + blockIdx.x / 8;
  const int bm = swz / (N3H / 128);
  const int bn = swz % (N3H / 128);
  const int lane = tid & 63;
  const int wid = tid >> 6;
  const int wm = (wid >> 1) * 64, wn = (wid & 1) * 64;

  const unsigned short* Ag = A + (size_t)bm * 128 * GK;
  const unsigned short* Bg = B + (size_t)bn * 128 * GK;

  const int s0 = tid, s1 = tid + 256;
  const int r0 = s0 >> 2, c0 = (s0 & 3) * 8;
  const int r1 = s1 >> 2, c1 = (s1 & 3) * 8;

  const int fr = lane & 15;         // fragment row (M for A, N for B)
  const int ko = (lane >> 4) * 8;   // fragment k offset (8 contiguous)

  f32x4 acc[4][4];
#pragma unroll
  for (int i = 0; i < 4; ++i)
#pragma unroll
    for (int j = 0; j < 4; ++j) acc[i][j] = (f32x4){0.f, 0.f, 0.f, 0.f};

#define STAGE(buf, k0)                                                                              \
  {                                                                                                 \
    __builtin_amdgcn_global_load_lds(                                                               \
        (const __attribute__((address_space(1))) void*)(Ag + (size_t)r0 * GK + (k0) + c0),          \
        (__attribute__((address_space(3))) void*)&lds[buf][s0 * 8], 16, 0, 0);                      \
    __builtin_amdgcn_global_load_lds(                                                               \
        (const __attribute__((address_space(1))) void*)(Ag + (size_t)r1 * GK + (k0) + c1),          \
        (__attribute__((address_space(3))) void*)&lds[buf][s1 * 8], 16, 0, 0);                      \
    __builtin_amdgcn_global_load_lds(                                                               \
        (const __attribute__((address_space(1))) void*)(Bg + (size_t)r0 * GK + (k0) + c0),          \
        (__attribute__((address_space(3))) void*)&lds[buf][4096 + s0 * 8], 16, 0, 0);               \
    __builtin_amdgcn_global_load_lds(                                                               \
        (const __attribute__((address_space(1))) void*)(Bg + (size_t)r1 * GK + (k0) + c1),          \
        (__attribute__((address_space(3))) void*)&lds[buf][4096 + s1 * 8], 16, 0, 0);               \
  }

  STAGE(0, 0);
  __syncthreads();
  int cur = 0;
#pragma unroll 1
  for (int kt = 0; kt < GK / 32; ++kt) {
    if (kt + 1 < GK / 32) STAGE(cur ^ 1, (kt + 1) * 32);
    f16x8 af[4], bfr[4];
#pragma unroll
    for (int t = 0; t < 4; ++t) {
      af[t]  = *(const f16x8*)&lds[cur][(wm + t * 16 + fr) * 32 + ko];
      bfr[t] = *(const f16x8*)&lds[cur][4096 + (wn + t * 16 + fr) * 32 + ko];
    }
#pragma unroll
    for (int mt = 0; mt < 4; ++mt)
#pragma unroll
      for (int nt = 0; nt < 4; ++nt)
        acc[mt][nt] = __builtin_amdgcn_mfma_f32_16x16x32_f16(af[mt], bfr[nt], acc[mt][nt], 0, 0, 0);
    if (kt + 1 < GK / 32) {
      __syncthreads();
      cur ^= 1;
    }
  }
#undef STAGE

  // ---- coalesced C-write via LDS transpose; row stride padded 128->136:
  // 272B rows spread the 4 er-row groups across bank halves (store-side
  // conflicts halved) and keep 16B alignment for the read-back.
  __syncthreads();
  unsigned short* cl = &lds[0][0];
  const int er = (lane >> 4) * 4;   // C/D layout: col=lane&15, row=(lane>>4)*4+reg
#pragma unroll
  for (int mt = 0; mt < 4; ++mt)
#pragma unroll
    for (int nt = 0; nt < 4; ++nt) {
      const int row = wm + mt * 16 + er;
      const int col = wn + nt * 16 + fr;
#pragma unroll
      for (int j = 0; j < 4; ++j) cl[(row + j) * 136 + col] = f2h(acc[mt][nt][j]);
    }
  __syncthreads();
  unsigned short* Cb = C + (size_t)bm * 128 * N3H + bn * 128;
#pragma unroll
  for (int i = 0; i < 8; ++i) {
    int flat = i * 2048 + tid * 8;
    int r = flat >> 7, c = flat & 127;
    *(u16x8*)(Cb + (size_t)r * N3H + c) = *(const u16x8*)&cl[r * 136 + c];
  }
}

// ---------------- Fused single-pass SRU scan (decoupled lookback) ----------------
// Grid: 64 segments x 16 batch = 1024 blocks; 256 thr x 2h = 512 chains/block.
// __launch_bounds__(256,4) => VGPR<=128 => 4 blocks/CU => ALL 1024 blocks
// resident from T0 (publish-before-wait => no deadlock).
// Protocol: per (segment, chain) publish (F, C) packed in ONE 64-bit word via
// atomicExch; F stored NEGATED so the low word's sign bit doubles as the
// "published" tag (F in [0,1], -0.0 still tagged). FC zeroed per layer.
__global__ __launch_bounds__(256, 4) void sru_scan_fused(
    const unsigned short* __restrict__ U,     // [L][B][3H] f16: xt | zf | zr
    const float* __restrict__ bias,           // [2H]
    unsigned long long* __restrict__ FC,      // [NSEG][B][H] packed, pre-zeroed
    unsigned short* hb) {                     // [L][B][H] f16, updated in place
  const int s = blockIdx.x >> 4;
  const int b = blockIdx.x & 15;
  const int h0 = threadIdx.x << 1;
  const float bf0 = bias[h0], bf1 = bias[h0 + 1];
  const float br0 = bias[HID + h0], br1 = bias[HID + h0 + 1];

  const size_t rowstep = (size_t)BATCH * N3H;
  const unsigned short* Up = U + ((size_t)(s * CHUNK) * BATCH + b) * N3H + h0;

  // ---- phase 1: local (F, C | c0=0); retain packed (f16 f, f16 xt) per step
  unsigned fx0[CHUNK], fx1[CHUNK];
  float F0 = 1.f, F1 = 1.f, c0 = 0.f, c1 = 0.f;
#pragma unroll
  for (int i = 0; i < CHUNK; ++i) {
    const unsigned short* p = Up + (size_t)i * rowstep;
    unsigned xt = *(const unsigned*)(p);
    unsigned zf = *(const unsigned*)(p + HID);
    // round f to f16 FIRST so phase-3 reconstruction is bit-consistent
    unsigned short fh0 = f2h(sigm(h2f((unsigned short)zf) + bf0));
    unsigned short fh1 = f2h(sigm(h2f((unsigned short)(zf >> 16)) + bf1));
    float f0 = h2f(fh0), f1 = h2f(fh1);
    c0 = f0 * c0 + (1.f - f0) * h2f((unsigned short)xt);
    c1 = f1 * c1 + (1.f - f1) * h2f((unsigned short)(xt >> 16));
    F0 *= f0; F1 *= f1;
    fx0[i] = (xt & 0xffffu) | ((unsigned)fh0 << 16);
    fx1[i] = (xt >> 16) | ((unsigned)fh1 << 16);
  }

  // ---- publish (single-word atomic; no fence needed)
  const size_t ch = ((size_t)s * BATCH + b) * HID + h0;
  atomicExch(&FC[ch],
             ((unsigned long long)__builtin_bit_cast(unsigned, c0) << 32) |
                 __builtin_bit_cast(unsigned, -F0));
  atomicExch(&FC[ch + 1],
             ((unsigned long long)__builtin_bit_cast(unsigned, c1) << 32) |
                 __builtin_bit_cast(unsigned, -F1));

  // ---- lookback: c_in = sum_{j<s} C_j * prod_{j<k<s} F_k
  float ci0 = 0.f, ci1 = 0.f, P0 = 1.f, P1 = 1.f;
  for (int j = s - 1; j >= 0; --j) {
    const size_t cj = ((size_t)j * BATCH + b) * HID + h0;
    unsigned long long v0, v1;
    do { v0 = atomicAdd(&FC[cj], 0ULL); } while (!(v0 & 0x80000000ULL));
    do { v1 = atomicAdd(&FC[cj + 1], 0ULL); } while (!(v1 & 0x80000000ULL));
    float Fj0 = -__builtin_bit_cast(float, (unsigned)v0);
    float Cj0 = __builtin_bit_cast(float, (unsigned)(v0 >> 32));
    float Fj1 = -__builtin_bit_cast(float, (unsigned)v1);
    float Cj1 = __builtin_bit_cast(float, (unsigned)(v1 >> 32));
    ci0 += P0 * Cj0; P0 *= Fj0;
    ci1 += P1 * Cj1; P1 *= Fj1;
    if (P0 == 0.f && P1 == 0.f) break;   // product underflow: rest contributes 0
  }

  // ---- phase 3: replay with carry; read zr + x, write h in place
  float cc0 = ci0, cc1 = ci1;
  const size_t hstep = (size_t)BATCH * HID;
  unsigned short* hp = hb + ((size_t)(s * CHUNK) * BATCH + b) * HID + h0;
#pragma unroll
  for (int i = 0; i < CHUNK; ++i) {
    unsigned zr = *(const unsigned*)(Up + (size_t)i * rowstep + 2 * HID);
    unsigned xv = *(const unsigned*)(hp + (size_t)i * hstep);
    float f0 = h2f((unsigned short)(fx0[i] >> 16));
    float f1 = h2f((unsigned short)(fx1[i] >> 16));
    cc0 = f0 * cc0 + (1.f - f0) * h2f((unsigned short)fx0[i]);
    cc1 = f1 * cc1 + (1.f - f1) * h2f((unsigned short)fx1[i]);
    float r0 = sigm(h2f((unsigned short)zr) + br0);
    float r1 = sigm(h2f((unsigned short)(zr >> 16)) + br1);
    float hn0 = r0 * cc0 + (1.f - r0) * h2f((unsigned short)xv);
    float hn1 = r1 * cc1 + (1.f - r1) * h2f((unsigned short)(xv >> 16));
    *(unsigned*)(hp + (size_t)i * hstep) = (unsigned)f2h(hn0) | ((unsigned)f2h(hn1) << 16);
  }
}

// ---------------- FC head (f16 H, f32 math) ----------------
#define FCR 16
__global__ __launch_bounds__(256) void fc_kernel(const unsigned short* __restrict__ H,
                                                 const float* __restrict__ W,
                                                 const float* __restrict__ bv,
                                                 float* __restrict__ out) {
  __shared__ float hs[FCR][516];
  __shared__ float ws[OUT_DIM][516];
  const int tid = threadIdx.x;
  const size_t m0 = (size_t)blockIdx.x * FCR;
#pragma unroll
  for (int i = 0; i < 4; ++i) {
    int f = tid + i * 256;
    int row = f >> 6;     // 0..15
    int kq = f & 63;      // 8-elem group
    u16x8 v = *(const u16x8*)(H + (m0 + row) * 512 + kq * 8);
#pragma unroll
    for (int j = 0; j < 8; ++j) hs[row][kq * 8 + j] = h2f(v[j]);
  }
#pragma unroll
  for (int i = 0; i < 5; ++i) {
    int f = tid + i * 256;
    int row = f >> 7;     // 0..9
    int kq = f & 127;
    float4 v = *(const float4*)(W + row * 512 + kq * 4);
    *(float4*)&ws[row][kq * 4] = v;
  }
  __syncthreads();
  if (tid < FCR * OUT_DIM) {
    int row = tid / OUT_DIM;
    int o = tid - row * OUT_DIM;
    float acc = bv[o];
#pragma unroll 8
    for (int k = 0; k < 512; ++k) acc += hs[row][k] * ws[o][k];
    out[(m0 + row) * OUT_DIM + o] = acc;
  }
}

extern "C" void kernel_launch(void* const* d_in, const int* in_sizes, int n_in,
                              void* d_out, int out_size, void* d_ws, size_t ws_size,
                              hipStream_t stream) {
  const float* x   = (const float*)d_in[0];  // [2048][16][512]
  const float* Ws  = (const float*)d_in[1];  // [5][1536][512]
  const float* bs  = (const float*)d_in[2];  // [5][1024]
  const float* fcW = (const float*)d_in[3];  // [10][512]
  const float* fcb = (const float*)d_in[4];  // [10]
  float* out = (float*)d_out;

  char* ws = (char*)d_ws;
  const size_t MiB = 1024 * 1024;
  unsigned short* Ub = (unsigned short*)ws;                  // 96 MiB: [M][1536] f16
  unsigned short* hb = (unsigned short*)(ws + 96 * MiB);     // 32 MiB: [M][512] f16
  unsigned short* Wh = (unsigned short*)(ws + 128 * MiB);    // 7.5 MiB f16 weights
  unsigned long long* FC = (unsigned long long*)(ws + 136 * MiB);  // 4 MiB lookback
  // total 140 MiB <= 256 MiB workspace

  // one-time converts (per call; inputs never mutated)
  cvt_f32_to_f16<<<(NLAYERS * N3H * HID) / (256 * 8), 256, 0, stream>>>(Ws, Wh);
  cvt_f32_to_f16<<<(M_ROWS * HID) / (256 * 8), 256, 0, stream>>>(x, hb);

  for (int l = 0; l < NLAYERS; ++l) {
    hipMemsetAsync(FC, 0, (size_t)NSEG * BATCH * HID * 8, stream);
    gemm_mfma<<<(M_ROWS / 128) * (N3H / 128), 256, 0, stream>>>(
        hb, Wh + (size_t)l * N3H * HID, Ub);
    sru_scan_fused<<<NSEG * BATCH, 256, 0, stream>>>(Ub, bs + (size_t)l * 2 * HID, FC, hb);
  }
  fc_kernel<<<M_ROWS / FCR, 256, 0, stream>>>(hb, fcW, fcb, out);
}